// Round 1
// baseline (205.165 us; speedup 1.0000x reference)
//
#include <hip/hip_runtime.h>
#include <cstdint>

#define BB 4
#define LL 2048
#define HH 16
#define DD 64
#define CHUNK 64
#define NC (LL/CHUNK)        // 32 chunks per (b,h)
#define NBH (BB*HH)          // 64
#define NBLK (NBH*NC)        // 2048 chunk tasks
#define LSTR (HH*DD)         // 1024 floats between consecutive l
#define TS 68                // padded transposed LDS stride (16B-aligned float4 rows)
#define EPSF 1e-6f

__device__ __forceinline__ float fmap(float x) {
    // elu(x) + 1
    return x > 0.0f ? x + 1.0f : __expf(x);
}

// ---------------- Kernel 1: per-chunk KV and Ksum ----------------
__global__ __launch_bounds__(256) void k1_chunk_sums(
    const float* __restrict__ kp, const float* __restrict__ vp,
    float* __restrict__ kv, float* __restrict__ ks)
{
    __shared__ float kf_s[CHUNK*DD];   // [l][d], feature-mapped
    __shared__ float v_s[CHUNK*DD];    // [l][m]
    const int ci = blockIdx.x;
    const int c  = ci & (NC-1);
    const int bh = ci >> 5;            // NC = 32
    const int b  = bh >> 4, h = bh & 15;
    const int t  = threadIdx.x;
    const int64_t gbase = ((int64_t)(b*LL + c*CHUNK)*HH + h)*DD;
#pragma unroll
    for (int i = 0; i < 4; ++i) {
        int flat = t + i*256;              // float4 index, 1024 total
        int l    = flat >> 4;              // 16 float4 per row
        int col  = (flat & 15) << 2;
        int64_t ga = gbase + (int64_t)l*LSTR + col;
        float4 kq = *(const float4*)(kp + ga);
        float4 vq = *(const float4*)(vp + ga);
        kq.x = fmap(kq.x); kq.y = fmap(kq.y); kq.z = fmap(kq.z); kq.w = fmap(kq.w);
        *(float4*)(kf_s + l*DD + col) = kq;
        *(float4*)(v_s  + l*DD + col) = vq;
    }
    __syncthreads();
    const int d0 = (t >> 4) << 2;
    const int m0 = (t & 15) << 2;
    float acc[4][4] = {};
#pragma unroll 8
    for (int l = 0; l < CHUNK; ++l) {
        float4 kq = *(const float4*)(kf_s + l*DD + d0);
        float4 vq = *(const float4*)(v_s  + l*DD + m0);
        const float kr[4] = {kq.x,kq.y,kq.z,kq.w};
        const float vr[4] = {vq.x,vq.y,vq.z,vq.w};
#pragma unroll
        for (int r = 0; r < 4; ++r)
#pragma unroll
            for (int cc = 0; cc < 4; ++cc)
                acc[r][cc] = fmaf(kr[r], vr[cc], acc[r][cc]);
    }
    float* kvo = kv + (int64_t)ci*DD*DD;   // KV[d][m]
#pragma unroll
    for (int r = 0; r < 4; ++r) {
        float4 o = {acc[r][0],acc[r][1],acc[r][2],acc[r][3]};
        *(float4*)(kvo + (d0+r)*DD + m0) = o;
    }
    if (t < DD) {
        float s = 0.f;
#pragma unroll 8
        for (int l = 0; l < CHUNK; ++l) s += kf_s[l*DD + t];
        ks[(int64_t)ci*DD + t] = s;
    }
}

// ---------------- Kernel 2: exclusive prefix over chunks (in-place) ----------------
__global__ __launch_bounds__(256) void k2_prefix(
    float* __restrict__ kv, float* __restrict__ ks)
{
    const int blk = blockIdx.x;        // NBH*4 = 256 blocks
    const int bh  = blk >> 2;
    const int qtr = blk & 3;
    const int t   = threadIdx.x;
    const int f4  = qtr*256 + t;       // float4 index within 4096-float tile
    float4 run = {0.f,0.f,0.f,0.f};
    float4* base = (float4*)kv + (int64_t)bh*NC*1024 + f4;
    for (int c = 0; c < NC; ++c) {
        float4* p = base + (int64_t)c*1024;
        float4 x = *p;
        *p = run;
        run.x += x.x; run.y += x.y; run.z += x.z; run.w += x.w;
    }
    if (qtr == 0 && t < DD) {
        float r = 0.f;
        float* kb = ks + (int64_t)bh*NC*DD + t;
        for (int c = 0; c < NC; ++c) {
            float x = kb[(int64_t)c*DD];
            kb[(int64_t)c*DD] = r;
            r += x;
        }
    }
}

// ---------------- Kernel 3: per-chunk output ----------------
__global__ __launch_bounds__(256) void k3_output(
    const float* __restrict__ qp, const float* __restrict__ kp,
    const float* __restrict__ vp, const float* __restrict__ kv,
    const float* __restrict__ ks, float* __restrict__ outp)
{
    __shared__ float qf_t[DD*TS];      // [d][l] transposed, padded
    __shared__ float kfA_t[DD*TS];     // kf transposed [d][s]; later reused as A_t[s][l]
    __shared__ float v_s[CHUNK*DD];    // [s][m]
    __shared__ float S_s[DD*DD];       // [d][m] chunk-prefix state
    __shared__ float z_s[CHUNK];
    __shared__ float kp_s[DD];
    const int ci = blockIdx.x;
    const int c  = ci & (NC-1);
    const int bh = ci >> 5;
    const int b  = bh >> 4, h = bh & 15;
    const int t  = threadIdx.x;
    const int64_t gbase = ((int64_t)(b*LL + c*CHUNK)*HH + h)*DD;
    const float* Sg = kv + (int64_t)ci*DD*DD;
#pragma unroll
    for (int i = 0; i < 4; ++i) {
        int flat = t + i*256;
        int l    = flat >> 4;
        int col  = (flat & 15) << 2;
        int64_t ga = gbase + (int64_t)l*LSTR + col;
        float4 qq = *(const float4*)(qp + ga);
        float4 kq = *(const float4*)(kp + ga);
        float4 vq = *(const float4*)(vp + ga);
        qf_t[(col+0)*TS + l] = fmap(qq.x);
        qf_t[(col+1)*TS + l] = fmap(qq.y);
        qf_t[(col+2)*TS + l] = fmap(qq.z);
        qf_t[(col+3)*TS + l] = fmap(qq.w);
        kfA_t[(col+0)*TS + l] = fmap(kq.x);
        kfA_t[(col+1)*TS + l] = fmap(kq.y);
        kfA_t[(col+2)*TS + l] = fmap(kq.z);
        kfA_t[(col+3)*TS + l] = fmap(kq.w);
        *(float4*)(v_s + l*DD + col) = vq;
        float4 sq = *(const float4*)(Sg + flat*4);
        *(float4*)(S_s + flat*4) = sq;
    }
    if (t < DD) kp_s[t] = ks[(int64_t)ci*DD + t];
    __syncthreads();

    const int l0 = (t >> 4) << 2;      // 4 output rows  (l)
    const int s0 = (t & 15) << 2;      // 4 cols (s), also m0 in phase 2
    // ---- A = qf * kf^T (4x4 tile per thread) ----
    float a[4][4] = {};
#pragma unroll 4
    for (int d = 0; d < DD; ++d) {
        float4 q4 = *(const float4*)(qf_t  + d*TS + l0);
        float4 k4 = *(const float4*)(kfA_t + d*TS + s0);
        const float qr[4] = {q4.x,q4.y,q4.z,q4.w};
        const float kr[4] = {k4.x,k4.y,k4.z,k4.w};
#pragma unroll
        for (int r = 0; r < 4; ++r)
#pragma unroll
            for (int cc = 0; cc < 4; ++cc)
                a[r][cc] = fmaf(qr[r], kr[cc], a[r][cc]);
    }
    // causal mask: keep s <= l
#pragma unroll
    for (int r = 0; r < 4; ++r)
#pragma unroll
        for (int cc = 0; cc < 4; ++cc)
            if (s0 + cc > l0 + r) a[r][cc] = 0.f;
    __syncthreads();                   // all kf_t reads complete before overwrite
    // store A transposed: A_t[s][l], overlaid on kfA_t
#pragma unroll
    for (int cc = 0; cc < 4; ++cc) {
        float4 colv = {a[0][cc], a[1][cc], a[2][cc], a[3][cc]};
        *(float4*)(kfA_t + (s0+cc)*TS + l0) = colv;
    }
    __syncthreads();
    // ---- z[l] = eps + sum_{s<=l} A[l][s] + qf[l].Kprefix ----
    if (t < CHUNK) {
        float z = EPSF;
#pragma unroll 8
        for (int s = 0; s < CHUNK; ++s) z += kfA_t[s*TS + t];   // masked zeros for s>l
#pragma unroll 8
        for (int d = 0; d < DD; ++d) z += qf_t[d*TS + t] * kp_s[d];
        z_s[t] = z;
    }
    __syncthreads();

    // ---- out = (A*v + qf*S) / z ----
    const int m0 = s0;
    float o[4][4] = {};
#pragma unroll 4
    for (int s = 0; s < CHUNK; ++s) {
        float4 a4 = *(const float4*)(kfA_t + s*TS + l0);
        float4 v4 = *(const float4*)(v_s   + s*DD + m0);
        const float ar[4] = {a4.x,a4.y,a4.z,a4.w};
        const float vr[4] = {v4.x,v4.y,v4.z,v4.w};
#pragma unroll
        for (int r = 0; r < 4; ++r)
#pragma unroll
            for (int cc = 0; cc < 4; ++cc)
                o[r][cc] = fmaf(ar[r], vr[cc], o[r][cc]);
    }
#pragma unroll 4
    for (int d = 0; d < DD; ++d) {
        float4 q4 = *(const float4*)(qf_t + d*TS + l0);
        float4 s4 = *(const float4*)(S_s  + d*DD + m0);
        const float qr[4] = {q4.x,q4.y,q4.z,q4.w};
        const float sr[4] = {s4.x,s4.y,s4.z,s4.w};
#pragma unroll
        for (int r = 0; r < 4; ++r)
#pragma unroll
            for (int cc = 0; cc < 4; ++cc)
                o[r][cc] = fmaf(qr[r], sr[cc], o[r][cc]);
    }
#pragma unroll
    for (int r = 0; r < 4; ++r) {
        float rz = 1.0f / z_s[l0 + r];
        float4 ov = {o[r][0]*rz, o[r][1]*rz, o[r][2]*rz, o[r][3]*rz};
        *(float4*)(outp + gbase + (int64_t)(l0+r)*LSTR + m0) = ov;
    }
}

extern "C" void kernel_launch(void* const* d_in, const int* in_sizes, int n_in,
                              void* d_out, int out_size, void* d_ws, size_t ws_size,
                              hipStream_t stream) {
    const float* q = (const float*)d_in[0];
    const float* k = (const float*)d_in[1];
    const float* v = (const float*)d_in[2];
    float* out  = (float*)d_out;
    float* kv   = (float*)d_ws;                         // NBLK * 64*64 floats (32 MiB)
    float* ksum = kv + (int64_t)NBLK*DD*DD;             // NBLK * 64 floats (512 KiB)
    k1_chunk_sums<<<NBLK, 256, 0, stream>>>(k, v, kv, ksum);
    k2_prefix<<<NBH*4, 256, 0, stream>>>(kv, ksum);
    k3_output<<<NBLK, 256, 0, stream>>>(q, k, v, kv, ksum, out);
}

// Round 2
// 157.668 us; speedup vs baseline: 1.3013x; 1.3013x over previous
//
#include <hip/hip_runtime.h>
#include <cstdint>

#define LL 2048
#define HH 16
#define DD 64
#define NC 32
#define LSTR 1024
#define EPSF 1e-6f
#define PAD 72   // bf16 elements per LDS row (36 words -> conflict-free b128 frags)

typedef __bf16 bf16x8 __attribute__((ext_vector_type(8)));
typedef float floatx4 __attribute__((ext_vector_type(4)));
typedef unsigned short ushortx8 __attribute__((ext_vector_type(8)));
typedef unsigned short ushortx4 __attribute__((ext_vector_type(4)));

static __device__ __forceinline__ float fmap(float x){ return x > 0.f ? x + 1.f : __expf(x); }
static __device__ __forceinline__ unsigned short f2bf(float f){
    unsigned u = __builtin_bit_cast(unsigned, f);
    u += 0x7fffu + ((u >> 16) & 1u);
    return (unsigned short)(u >> 16);
}
static __device__ __forceinline__ float bf2f(unsigned short s){
    unsigned u = ((unsigned)s) << 16;
    return __builtin_bit_cast(float, u);
}
static __device__ __forceinline__ bf16x8 ldf(const unsigned short* p){
    return __builtin_bit_cast(bf16x8, *(const ushortx8*)p);
}

// ---------------- k1: per-chunk KVt[m][d] (bf16) + Ksum (fp32), via MFMA ----------------
__global__ __launch_bounds__(256) void k1(const float* __restrict__ kp, const float* __restrict__ vp,
                                          unsigned short* __restrict__ kvt, float* __restrict__ ks)
{
    __shared__ __align__(16) unsigned short kft[DD*PAD]; // kf^T: [d][s]
    __shared__ __align__(16) unsigned short vts[DD*PAD]; // v^T:  [m][s]
    const int ci = blockIdx.x;
    const int c = ci & 31, bh = ci >> 5, b = bh >> 4, h = bh & 15;
    const int t = threadIdx.x;
    const int64_t gbase = ((int64_t)(b*LL + c*DD)*HH + h)*DD;
#pragma unroll
    for (int i = 0; i < 4; ++i) {
        int flat = t + 256*i;
        int l = flat >> 4, col = (flat & 15) << 2;
        float4 kq = *(const float4*)(kp + gbase + (int64_t)l*LSTR + col);
        float4 vq = *(const float4*)(vp + gbase + (int64_t)l*LSTR + col);
        kft[(col+0)*PAD + l] = f2bf(fmap(kq.x));
        kft[(col+1)*PAD + l] = f2bf(fmap(kq.y));
        kft[(col+2)*PAD + l] = f2bf(fmap(kq.z));
        kft[(col+3)*PAD + l] = f2bf(fmap(kq.w));
        vts[(col+0)*PAD + l] = f2bf(vq.x);
        vts[(col+1)*PAD + l] = f2bf(vq.y);
        vts[(col+2)*PAD + l] = f2bf(vq.z);
        vts[(col+3)*PAD + l] = f2bf(vq.w);
    }
    __syncthreads();
    const int w = t >> 6, lane = t & 63, quad = lane >> 4, lr = lane & 15;
    const int m0 = 16*w;
    floatx4 acc[4];
#pragma unroll
    for (int dt = 0; dt < 4; ++dt) acc[dt] = floatx4{0.f,0.f,0.f,0.f};
#pragma unroll
    for (int kk = 0; kk < 2; ++kk) {
        bf16x8 a = ldf(vts + (m0+lr)*PAD + kk*32 + quad*8);
#pragma unroll
        for (int dt = 0; dt < 4; ++dt) {
            bf16x8 bb = ldf(kft + (dt*16+lr)*PAD + kk*32 + quad*8);
            acc[dt] = __builtin_amdgcn_mfma_f32_16x16x32_bf16(a, bb, acc[dt], 0, 0, 0);
        }
    }
    unsigned short* kvo = kvt + (int64_t)ci*4096;   // [m][d] bf16
#pragma unroll
    for (int dt = 0; dt < 4; ++dt)
#pragma unroll
        for (int r = 0; r < 4; ++r)
            kvo[(m0 + quad*4 + r)*DD + dt*16 + lr] = f2bf(acc[dt][r]);
    if (t < DD) {
        float s = 0.f;
#pragma unroll
        for (int j = 0; j < 8; ++j) {
            ushortx8 u = *(const ushortx8*)(kft + t*PAD + j*8);
#pragma unroll
            for (int e = 0; e < 8; ++e) s += bf2f(u[e]);
        }
        ks[(int64_t)ci*DD + t] = s;
    }
}

// ---------------- k2: exclusive prefix over chunks (bf16 kv, fp32 carry) ----------------
__global__ __launch_bounds__(256) void k2(unsigned short* __restrict__ kvt, float* __restrict__ ks)
{
    const int blk = blockIdx.x;          // 128 = 64 bh * 2 halves
    const int bh = blk >> 1, half = blk & 1, t = threadIdx.x;
    const int g8 = half*256 + t;         // 0..511 ushort8 groups of a 4096-elem tile
    unsigned short* base = kvt + (int64_t)bh*NC*4096 + g8*8;
    float run[8] = {0,0,0,0,0,0,0,0};
    ushortx8 x = *(const ushortx8*)(base);
    for (int c = 0; c < NC-1; ++c) {
        ushortx8 xn = *(const ushortx8*)(base + (int64_t)(c+1)*4096);
        ushortx8 o;
#pragma unroll
        for (int e = 0; e < 8; ++e) { o[e] = f2bf(run[e]); run[e] += bf2f(x[e]); }
        *(ushortx8*)(base + (int64_t)c*4096) = o;
        x = xn;
    }
    {
        ushortx8 o;
#pragma unroll
        for (int e = 0; e < 8; ++e) o[e] = f2bf(run[e]);
        *(ushortx8*)(base + (int64_t)(NC-1)*4096) = o;
    }
    if (half == 0 && t < DD) {
        float r = 0.f;
        float* kb = ks + (int64_t)bh*NC*DD + t;
        for (int c = 0; c < NC; ++c) { float xx = kb[(int64_t)c*DD]; kb[(int64_t)c*DD] = r; r += xx; }
    }
}

// ---------------- k3: per-chunk output via 3 MFMA GEMMs ----------------
__global__ __launch_bounds__(256) void k3(const float* __restrict__ qp, const float* __restrict__ kp,
                                          const float* __restrict__ vp,
                                          const unsigned short* __restrict__ kvt,
                                          const float* __restrict__ ks, float* __restrict__ outp)
{
    __shared__ __align__(16) unsigned short qf [DD*PAD];  // [l][d]
    __shared__ __align__(16) unsigned short kfx[80*PAD];  // [s][d]; row64=Kprefix, 65-79=0
    __shared__ __align__(16) unsigned short vts[DD*PAD];  // v^T [m][s]
    __shared__ __align__(16) unsigned short stp[DD*PAD];  // S^T [m][d]  (= KVt)
    __shared__ __align__(16) unsigned short asx[DD*PAD];  // masked scores [l][s]
    __shared__ float zr[DD];
    const int ci = blockIdx.x;
    const int c = ci & 31, bh = ci >> 5, b = bh >> 4, h = bh & 15;
    const int t = threadIdx.x;
    const int64_t gbase = ((int64_t)(b*LL + c*DD)*HH + h)*DD;
    const unsigned short* kvg = kvt + (int64_t)ci*4096;
    const float* ksg = ks + (int64_t)ci*DD;
#pragma unroll
    for (int i = 0; i < 4; ++i) {
        int flat = t + 256*i;
        int l = flat >> 4, col = (flat & 15) << 2;
        float4 qq = *(const float4*)(qp + gbase + (int64_t)l*LSTR + col);
        float4 kq = *(const float4*)(kp + gbase + (int64_t)l*LSTR + col);
        float4 vq = *(const float4*)(vp + gbase + (int64_t)l*LSTR + col);
        ushortx4 qb = { f2bf(fmap(qq.x)), f2bf(fmap(qq.y)), f2bf(fmap(qq.z)), f2bf(fmap(qq.w)) };
        ushortx4 kb = { f2bf(fmap(kq.x)), f2bf(fmap(kq.y)), f2bf(fmap(kq.z)), f2bf(fmap(kq.w)) };
        *(ushortx4*)(qf  + l*PAD + col) = qb;
        *(ushortx4*)(kfx + l*PAD + col) = kb;
        vts[(col+0)*PAD + l] = f2bf(vq.x);
        vts[(col+1)*PAD + l] = f2bf(vq.y);
        vts[(col+2)*PAD + l] = f2bf(vq.z);
        vts[(col+3)*PAD + l] = f2bf(vq.w);
    }
#pragma unroll
    for (int i = 0; i < 2; ++i) {
        int g = t + 256*i;                       // 512 ushort8 groups
        int m = g >> 3, off = (g & 7) << 3;
        *(ushortx8*)(stp + m*PAD + off) = *(const ushortx8*)(kvg + g*8);
    }
    if (t < 135) *(ushortx8*)(kfx + 65*PAD + t*8) = ushortx8{0,0,0,0,0,0,0,0};
    if (t < DD)  kfx[64*PAD + t] = f2bf(ksg[t]);
    __syncthreads();

    const int w = t >> 6, lane = t & 63, quad = lane >> 4, lr = lane & 15;
    const int l0 = 16*w;
    // ---- GEMM1: scores = qf * kf^T, plus Kprefix column (tile 4) ----
    bf16x8 aq[2];
    aq[0] = ldf(qf + (l0+lr)*PAD + quad*8);
    aq[1] = ldf(qf + (l0+lr)*PAD + 32 + quad*8);
    floatx4 sc[5];
#pragma unroll
    for (int tt = 0; tt < 5; ++tt) sc[tt] = floatx4{0.f,0.f,0.f,0.f};
#pragma unroll
    for (int kk = 0; kk < 2; ++kk)
#pragma unroll
        for (int tt = 0; tt < 5; ++tt) {
            bf16x8 bb = ldf(kfx + (tt*16+lr)*PAD + kk*32 + quad*8);
            sc[tt] = __builtin_amdgcn_mfma_f32_16x16x32_bf16(aq[kk], bb, sc[tt], 0, 0, 0);
        }
    // ---- causal mask, z row-sums, write masked A to LDS ----
    float zp[4] = {0.f,0.f,0.f,0.f};
#pragma unroll
    for (int tt = 0; tt < 4; ++tt)
#pragma unroll
        for (int r = 0; r < 4; ++r) {
            int row = l0 + quad*4 + r;
            int col = tt*16 + lr;
            float val = (col <= row) ? sc[tt][r] : 0.f;
            zp[r] += val;
            asx[row*PAD + col] = f2bf(val);
        }
#pragma unroll
    for (int r = 0; r < 4; ++r) zp[r] += (lr == 0) ? sc[4][r] : 0.f;   // col 64 = qf.Kprefix
#pragma unroll
    for (int m = 1; m < 16; m <<= 1)
#pragma unroll
        for (int r = 0; r < 4; ++r) zp[r] += __shfl_xor(zp[r], m, 64);
    if (lr == 0)
#pragma unroll
        for (int r = 0; r < 4; ++r) zr[l0 + quad*4 + r] = 1.f / (zp[r] + EPSF);
    __syncthreads();

    // ---- GEMM2: out = Amask * v + qf * S ----
    floatx4 oa[4];
#pragma unroll
    for (int mt = 0; mt < 4; ++mt) oa[mt] = floatx4{0.f,0.f,0.f,0.f};
#pragma unroll
    for (int kk = 0; kk < 2; ++kk) {
        bf16x8 a2 = ldf(asx + (l0+lr)*PAD + kk*32 + quad*8);
#pragma unroll
        for (int mt = 0; mt < 4; ++mt) {
            bf16x8 bv = ldf(vts + (mt*16+lr)*PAD + kk*32 + quad*8);
            oa[mt] = __builtin_amdgcn_mfma_f32_16x16x32_bf16(a2, bv, oa[mt], 0, 0, 0);
        }
    }
#pragma unroll
    for (int kk = 0; kk < 2; ++kk)
#pragma unroll
        for (int mt = 0; mt < 4; ++mt) {
            bf16x8 bs = ldf(stp + (mt*16+lr)*PAD + kk*32 + quad*8);
            oa[mt] = __builtin_amdgcn_mfma_f32_16x16x32_bf16(aq[kk], bs, oa[mt], 0, 0, 0);
        }
#pragma unroll
    for (int r = 0; r < 4; ++r) {
        int row = l0 + quad*4 + r;
        float rz = zr[row];
#pragma unroll
        for (int mt = 0; mt < 4; ++mt)
            outp[gbase + (int64_t)row*LSTR + mt*16 + lr] = oa[mt][r] * rz;
    }
}

extern "C" void kernel_launch(void* const* d_in, const int* in_sizes, int n_in,
                              void* d_out, int out_size, void* d_ws, size_t ws_size,
                              hipStream_t stream) {
    const float* q = (const float*)d_in[0];
    const float* k = (const float*)d_in[1];
    const float* v = (const float*)d_in[2];
    float* out = (float*)d_out;
    unsigned short* kvt = (unsigned short*)d_ws;          // 2048*4096 bf16 = 16 MiB
    float* ks = (float*)((char*)d_ws + (size_t)2048*4096*2);  // 2048*64 fp32 = 512 KiB
    k1<<<2048, 256, 0, stream>>>(k, v, kvt, ks);
    k2<<<128,  256, 0, stream>>>(kvt, ks);
    k3<<<2048, 256, 0, stream>>>(q, k, v, kvt, ks, out);
}